// Round 11
// baseline (193.548 us; speedup 1.0000x reference)
//
#include <hip/hip_runtime.h>
#include <hip/hip_bf16.h>
#include <math.h>

#define N_NODES 50000
#define N_EDGES 800000
#define C 64
#define EPS_F 1.000001f

// ---- round-25: uniform blocks — every block does scatter AND gemm-pre ----
// Ledger fix: gather has been ~55us all along (absent from top-5); K1 ~60
// is the top dispatch. r20 (half per-block edges, 2x blocks) was FLAT ->
// the scatter wall is invariant to per-block work; every variant shared
// one trait: after the pre role retires (~11us), scatter blocks straggle
// at ~2 waves/SIMD on an 80%-idle machine. Untested axis: co-schedule the
// edge pipeline with the GEMM FMA stream on EVERY CU for the WHOLE kernel.
// 392 uniform blocks x 1024 thr (16 waves): 4096 edges (4/thread, barriers
// done in the first ~3us) then 128 GEMM rows barrier-free -> no tail.
// Pass-B cursors padded one-per-line (r19: proven neutral; density here is
// ~980 RMW/line). Records/arithmetic/overflow identical to round 4.
// Gather = round-4 v10 verbatim (measured best total 174.5).
#define CAPN 48
#define OVF_IDX 0                     // cnt[0] = global overflow cursor
#define OMAX 4096
#define LOVF 64                       // block-local bucket-spill capacity

#define CPAD 16                       // ints per padded cursor (64 B line)

#define RB_BITS 7
#define RBUK (1 << RB_BITS)                   // 128 buckets per region
#define NBUCK (2 * N_NODES)                   // 100000 buckets
#define NREG ((NBUCK + RBUK - 1) >> RB_BITS)  // 782 regions (last partial)
#define RCAP 2560                             // lambda=2048, +11sigma
#define EPB 4096                              // edges per block (4/thread)
#define NK1 392                               // uniform blocks (392*4096>=2E)
#define ROWB 128                              // gemm rows per block

#define ZERON (CPAD * (NREG + 1))     // ovf line + padded region cursors

typedef __attribute__((ext_vector_type(8))) unsigned short u16x8;

__device__ __forceinline__ unsigned short f2bf(float f) {
    unsigned u = __float_as_uint(f);
    return (unsigned short)((u + 0x7FFFu + ((u >> 16) & 1u)) >> 16);
}
__device__ __forceinline__ float bf2f(unsigned short b) {
    return __uint_as_float(((unsigned)b) << 16);
}

// ---------------------------------------------------------------------------
// Kernel 1 (uniform): per block = 4096-edge scatter + 128-row GEMM pre.
//   pass A: 4 edges/thread, coalesced reads, LDS hist atomic, records
//           {j<<16|bf16(v)} in regs.
//   pass B: t<782: one padded global atomicAdd (count -> base).
//   pass C: LDS cursor atomic -> 8B store into shared region chunk.
//   gemm  : 16 waves x 8 rows, wave-uniform row ptrs -> scalar x loads;
//           f32 accs -> xm_l/xm_u/xlin + 4 shuffle-reduce s-dots.
// Edge pipeline latency hides under the GEMM FMA stream on every CU.
// ---------------------------------------------------------------------------
__global__ __launch_bounds__(1024) void fused_kernel(
    const float* __restrict__ x,
    const float* __restrict__ w_l, const float* __restrict__ a_l,
    const float* __restrict__ w_u, const float* __restrict__ a_u,
    const float* __restrict__ w_lin,
    const int* __restrict__ lidx, const float* __restrict__ lval,
    const int* __restrict__ uidx, const float* __restrict__ uval,
    unsigned short* __restrict__ xm_l, unsigned short* __restrict__ xm_u,
    float* __restrict__ xlin,
    float* __restrict__ ssl, float* __restrict__ stl,
    float* __restrict__ ssu, float* __restrict__ stu,
    int* __restrict__ cnt, uint2* __restrict__ rbuf, int2* __restrict__ ovf)
{
    const int b = blockIdx.x, t = threadIdx.x;
    __shared__ int hist[NREG];        // 3.1 KB; count -> base/cursor in place

    // ---- scatter: pass A ----
    for (int s0 = t; s0 < NREG; s0 += 1024) hist[s0] = 0;
    __syncthreads();

    unsigned lo[4];
    int bk[4];
    const int gbase = b * EPB + t;
#pragma unroll
    for (int k = 0; k < 4; ++k) {
        const int g = gbase + k * 1024;
        bk[k] = -1;
        if (g < 2 * N_EDGES) {
            int i, j;
            float v;
            if (g < N_EDGES) {
                i = lidx[g]; j = lidx[N_EDGES + g]; v = lval[g];
                bk[k] = 2 * i;
            } else {
                const int e = g - N_EDGES;
                i = uidx[e]; j = uidx[N_EDGES + e]; v = uval[e];
                bk[k] = 2 * i + 1;
            }
            lo[k] = ((unsigned)j << 16) | (unsigned)f2bf(v);
            atomicAdd(&hist[bk[k] >> RB_BITS], 1);
        }
    }
    __syncthreads();

    // ---- scatter: pass B (padded cursors, one per 64B line) ----
    if (t < NREG) {
        const int c = hist[t];
        hist[t] = c ? atomicAdd(&cnt[CPAD + t * CPAD], c) : 0;
    }
    __syncthreads();

    // ---- scatter: pass C ----
#pragma unroll
    for (int k = 0; k < 4; ++k) {
        if (bk[k] >= 0) {
            const int cb = bk[k] >> RB_BITS;
            const int slot = atomicAdd(&hist[cb], 1);     // LDS cursor
            if (slot < RCAP) {
                rbuf[(size_t)cb * RCAP + slot] = make_uint2(lo[k], (unsigned)bk[k]);
            } else {
                const int oi = atomicAdd(&cnt[OVF_IDX], 1);
                if (oi < OMAX) ovf[oi] = make_int2(bk[k], (int)lo[k]);
            }
        }
    }

    // ---- gemm pre: rows b*128 .. +127 (16 waves x 8 rows), no barriers ----
    const int lane = t & 63;
    const int wvu = __builtin_amdgcn_readfirstlane(t >> 6);
    const int row0 = b * ROWB + wvu * 8;
    if (row0 >= N_NODES) return;

    const float* xr[8];
#pragma unroll
    for (int r = 0; r < 8; ++r) {
        int rr = row0 + r;
        if (rr >= N_NODES) rr = N_NODES - 1;
        xr[r] = x + (size_t)rr * C;
    }

    float acc_l[8] = {0,0,0,0,0,0,0,0};
    float acc_u[8] = {0,0,0,0,0,0,0,0};
    float acc_n[8] = {0,0,0,0,0,0,0,0};

#pragma unroll 1
    for (int kc = 0; kc < C; kc += 4) {
#pragma unroll
        for (int kk = 0; kk < 4; ++kk) {
            const int k = kc + kk;
            const float wl = w_l[k * C + lane];
            const float wu = w_u[k * C + lane];
            const float wn = w_lin[k * C + lane];
#pragma unroll
            for (int r = 0; r < 8; ++r) {
                const float xk = xr[r][k];      // wave-uniform -> scalar load
                acc_l[r] = fmaf(xk, wl, acc_l[r]);
                acc_u[r] = fmaf(xk, wu, acc_u[r]);
                acc_n[r] = fmaf(xk, wn, acc_n[r]);
            }
        }
    }

    // a-vectors for the fused s-dots (coalesced, L2-hot)
    const float als = a_l[lane], alt = a_l[C + lane];
    const float aus = a_u[lane], aut = a_u[C + lane];

#pragma unroll
    for (int r = 0; r < 8; ++r) {
        const int row = row0 + r;
        if (row < N_NODES) {
            xm_l[row * C + lane] = f2bf(acc_l[r]);
            xm_u[row * C + lane] = f2bf(acc_u[r]);
            xlin[row * C + lane] = acc_n[r] * EPS_F;

            // s-dots: ssl = xm_l_row . a_l[:64], stl = xm_l_row . a_l[64:]
            float psl = acc_l[r] * als, ptl = acc_l[r] * alt;
            float psu = acc_u[r] * aus, ptu = acc_u[r] * aut;
#pragma unroll
            for (int o = 32; o >= 1; o >>= 1) {
                psl += __shfl_xor(psl, o);
                ptl += __shfl_xor(ptl, o);
                psu += __shfl_xor(psu, o);
                ptu += __shfl_xor(ptu, o);
            }
            if (lane == 0) {
                ssl[row] = psl; stl[row] = ptl;
                ssu[row] = psu; stu[row] = ptu;
            }
        }
    }
}

// ---------------------------------------------------------------------------
// Kernel 2: gather v10 (round-4 verbatim) — one block per REGION.
// Phase 1: coalesced read of the region's dense chunk, LDS-atomic sort into
//          128 LDS lists; bucket spills -> local LDS list.
// Phase 2: per node, interleaved conv-0/conv-1 walk; records carry
//          {j | bf16(v)}; alpha = elu(ssl[j] + stl[node]) * v inline.
// ---------------------------------------------------------------------------
__global__ __launch_bounds__(512) void gather_kernel(
    const float* __restrict__ xlin,
    const int* __restrict__ cnt, const uint2* __restrict__ rbuf,
    const int2* __restrict__ ovf,
    const unsigned short* __restrict__ xm_l, const unsigned short* __restrict__ xm_u,
    const float* __restrict__ ssl, const float* __restrict__ stl,
    const float* __restrict__ ssu, const float* __restrict__ stu,
    float* __restrict__ out)
{
    const int cb = blockIdx.x;
    const int t = threadIdx.x;
    const int wv = t >> 6, lane = t & 63;
    const int sub8 = lane >> 3;
    const int cg = lane & 7;

    __shared__ unsigned lists[RBUK * CAPN];  // 24.6 KB
    __shared__ int cur[RBUK];
    __shared__ int lovf_bk[LOVF];
    __shared__ unsigned lovf_rc[LOVF];
    __shared__ int lc;

    for (int s0 = t; s0 < RBUK; s0 += 512) cur[s0] = 0;
    if (t == 0) lc = 0;
    __syncthreads();

    // ---- phase 1: distribute region chunk into LDS lists ----
    const int n = min(cnt[CPAD + cb * CPAD], RCAP);
    const uint2* __restrict__ rb = rbuf + (size_t)cb * RCAP;
    for (int r = t; r < n; r += 512) {
        const uint2 e = rb[r];
        const int local = (int)e.y & (RBUK - 1);
        const int rank = atomicAdd(&cur[local], 1);
        if (rank < CAPN) {
            lists[local * CAPN + rank] = e.x;
        } else {
            const int o = atomicAdd(&lc, 1);
            if (o < LOVF) { lovf_bk[o] = local; lovf_rc[o] = e.x; }
        }
    }
    __syncthreads();

    const int oc = min(cnt[OVF_IDX], OMAX);
    const int lc2 = min(lc, LOVF);

    // ---- phase 2: per-node interleaved walk out of LDS ----
#pragma unroll 1
    for (int p = 0; p < 8; ++p) {
        const int q = wv * 8 + p;
        const int node = cb * 64 + q;
        if (node >= N_NODES) break;
        const int lA = 2 * q, lB = 2 * q + 1;
        const int lenA = min(cur[lA], CAPN);
        const int lenB = min(cur[lB], CAPN);
        const unsigned* __restrict__ lstA = lists + lA * CAPN;
        const unsigned* __restrict__ lstB = lists + lB * CAPN;

        const float stlN = stl[node];
        const float stuN = stu[node];

        float acc[8] = {0.f,0.f,0.f,0.f,0.f,0.f,0.f,0.f};
        int kA = 0, kB = 0;
        while ((kA < lenA) | (kB < lenB)) {
            const int iA = kA + sub8, iB = kB + sub8;
            const bool aA = iA < lenA, aB = iB < lenB;
            const unsigned rwA = lstA[aA ? iA : kA];
            const unsigned rwB = lstB[aB ? iB : kB];
            const int jA = aA ? (int)(rwA >> 16) : 0;
            const int jB = aB ? (int)(rwB >> 16) : 0;
            const float vA = aA ? bf2f((unsigned short)(rwA & 0xFFFFu)) : 0.f;
            const float vB = aB ? bf2f((unsigned short)(rwB & 0xFFFFu)) : 0.f;
            // alpha = elu(s_src[j] + s_tgt[i]) * v   (vA=0 kills inactive lanes)
            const float sA = ssl[jA] + stlN;
            const float sB = ssu[jB] + stuN;
            const float eA = (sA > 0.f) ? sA : expm1f(sA);
            const float eB = (sB > 0.f) ? sB : expm1f(sB);
            const float wA = eA * vA;
            const float wB = eB * vB;
            const u16x8 rowA = *(const u16x8*)(xm_l + jA * C + cg * 8);
            const u16x8 rowB = *(const u16x8*)(xm_u + jB * C + cg * 8);
#pragma unroll
            for (int c = 0; c < 8; ++c)
                acc[c] = fmaf(wA, bf2f(rowA[c]), acc[c]);
#pragma unroll
            for (int c = 0; c < 8; ++c)
                acc[c] = fmaf(wB, bf2f(rowB[c]), acc[c]);
            kA += (kA < lenA) ? 8 : 0;
            kB += (kB < lenB) ? 8 : 0;
        }

        // global (region-spill) overflow tail — expected empty
        for (int u = 0; u < oc; ++u) {
            const int2 e = ovf[u];
            if (e.x == 2 * node || e.x == 2 * node + 1) {
                const unsigned rw = (unsigned)e.y;
                const int j = (int)(rw >> 16);
                const float v = bf2f((unsigned short)(rw & 0xFFFFu));
                const int cv = e.x & 1;
                const float s = (cv ? ssu[j] : ssl[j]) + (cv ? stuN : stlN);
                const float el = (s > 0.f) ? s : expm1f(s);
                const float w = (sub8 == 0) ? el * v : 0.f;
                const unsigned short* xm = cv ? xm_u : xm_l;
                const u16x8 row = *(const u16x8*)(xm + j * C + cg * 8);
#pragma unroll
                for (int c = 0; c < 8; ++c)
                    acc[c] = fmaf(w, bf2f(row[c]), acc[c]);
            }
        }

        // local (bucket-spill) overflow tail — expected empty
        for (int u = 0; u < lc2; ++u) {
            const int bkl = lovf_bk[u];
            if (bkl == lA || bkl == lB) {
                const unsigned rw = lovf_rc[u];
                const int j = (int)(rw >> 16);
                const float v = bf2f((unsigned short)(rw & 0xFFFFu));
                const int cv = bkl & 1;
                const float s = (cv ? ssu[j] : ssl[j]) + (cv ? stuN : stlN);
                const float el = (s > 0.f) ? s : expm1f(s);
                const float w = (sub8 == 0) ? el * v : 0.f;
                const unsigned short* xm = cv ? xm_u : xm_l;
                const u16x8 row = *(const u16x8*)(xm + j * C + cg * 8);
#pragma unroll
                for (int c = 0; c < 8; ++c)
                    acc[c] = fmaf(w, bf2f(row[c]), acc[c]);
            }
        }

        // reduce over the 8 record slots (lane bits 3..5)
#pragma unroll
        for (int o = 8; o <= 32; o <<= 1)
#pragma unroll
            for (int c = 0; c < 8; ++c)
                acc[c] += __shfl_xor(acc[c], o);

        if (lane < 8) {
            const float* __restrict__ xl = xlin + (size_t)node * C + lane * 8;
            const float4 xa = *(const float4*)(xl);
            const float4 xb = *(const float4*)(xl + 4);
            float4 oa, ob;
            oa.x = fmaxf(acc[0] + xa.x, 0.f);
            oa.y = fmaxf(acc[1] + xa.y, 0.f);
            oa.z = fmaxf(acc[2] + xa.z, 0.f);
            oa.w = fmaxf(acc[3] + xa.w, 0.f);
            ob.x = fmaxf(acc[4] + xb.x, 0.f);
            ob.y = fmaxf(acc[5] + xb.y, 0.f);
            ob.z = fmaxf(acc[6] + xb.z, 0.f);
            ob.w = fmaxf(acc[7] + xb.w, 0.f);
            float* __restrict__ op = out + (size_t)node * C + lane * 8;
            *(float4*)(op) = oa;
            *(float4*)(op + 4) = ob;
        }
    }
}

extern "C" void kernel_launch(void* const* d_in, const int* in_sizes, int n_in,
                              void* d_out, int out_size, void* d_ws, size_t ws_size,
                              hipStream_t stream)
{
    const float* x          = (const float*)d_in[0];
    const int*   lower_idx  = (const int*)d_in[1];
    const float* lower_vals = (const float*)d_in[2];
    const int*   upper_idx  = (const int*)d_in[3];
    const float* upper_vals = (const float*)d_in[4];
    const float* w_lower    = (const float*)d_in[5];
    const float* a_lower    = (const float*)d_in[6];
    const float* w_upper    = (const float*)d_in[7];
    const float* a_upper    = (const float*)d_in[8];
    const float* w_lin      = (const float*)d_in[9];

    float* out = (float*)d_out;
    char* ws = (char*)d_ws;

    // ---- workspace layout (~43 MB) ----
    const size_t NC_F = (size_t)N_NODES * C * sizeof(float);
    const size_t NC_H = (size_t)N_NODES * C * sizeof(unsigned short);
    unsigned short* xm_l = (unsigned short*)ws;  ws += NC_H;
    unsigned short* xm_u = (unsigned short*)ws;  ws += NC_H;
    float* xlin = (float*)ws;                 ws += NC_F;
    float* ssl  = (float*)ws;                 ws += N_NODES * sizeof(float);
    float* stl  = (float*)ws;                 ws += N_NODES * sizeof(float);
    float* ssu  = (float*)ws;                 ws += N_NODES * sizeof(float);
    float* stu  = (float*)ws;                 ws += N_NODES * sizeof(float);
    int2* ovf   = (int2*)ws;                  ws += OMAX * sizeof(int2);
    uint2* rbuf = (uint2*)ws;                 ws += (size_t)NREG * RCAP * sizeof(uint2); // 16.0 MB
    int* cnt    = (int*)ws;                   ws += (size_t)(ZERON + 64) * sizeof(int);  // 50 KB

    // K0: zero cursors (ovf line + padded region cursors) — 50 KB
    hipMemsetAsync(cnt, 0, ZERON * sizeof(int), stream);

    // K1: uniform fused scatter + GEMM pre (edge latency hides under FMA)
    fused_kernel<<<NK1, 1024, 0, stream>>>(
        x, w_lower, a_lower, w_upper, a_upper, w_lin,
        lower_idx, lower_vals, upper_idx, upper_vals,
        xm_l, xm_u, xlin, ssl, stl, ssu, stu, cnt, rbuf, ovf);

    // K2: gather v10 (round-4 verbatim) + skip + relu
    gather_kernel<<<NREG, 512, 0, stream>>>(
        xlin, cnt, rbuf, ovf, xm_l, xm_u, ssl, stl, ssu, stu, out);
}